// Round 9
// baseline (1333.825 us; speedup 1.0000x reference)
//
#include <hip/hip_runtime.h>

#define N_NODESC 50000
#define N_EDGESC 400000
#define N_GRAPHSC 128
#define IN_DIMC 768
#define HIDC 128
#define NCLSC 11
#define BN_EPSC 1e-5f
#define NB_AGG 8
#define NREP 64
#define SCAN_NB ((N_NODESC + 255) / 256)

typedef __bf16 bf16_t;
typedef __bf16 bf16x2 __attribute__((ext_vector_type(2)));
typedef __bf16 bf16x8 __attribute__((ext_vector_type(8)));
typedef float f32x4 __attribute__((ext_vector_type(4)));

typedef __attribute__((address_space(1))) void glb_void;
typedef __attribute__((address_space(3))) void lds_void;

__device__ __forceinline__ void cp16(const void* g, void* l) {
    // async global->LDS, 16B/lane; LDS dst = wave-uniform base + lane*16
    __builtin_amdgcn_global_load_lds((glb_void*)g, (lds_void*)l, 16, 0, 0);
}

__device__ __forceinline__ f32x4 mfma_16x16x32_bf16(bf16x8 a, bf16x8 b, f32x4 c) {
    return __builtin_amdgcn_mfma_f32_16x16x32_bf16(a, b, c, 0, 0, 0);
}

// [Cl|Cr] = BN?(A)[M,K] @ Wb^T, Wb [256,K] bf16. Tile 128x128xBK32, grid (M/128, 2).
// Depth-2 async pipeline: A triple-buffered, B double (MODE0) / triple (MODE1);
// per-wave FIFO: prologue A0,B0,A1; loop stages B(it+1) then A(it+2) (MODE0) or
// (A,B)(it+2) (MODE1); raw s_waitcnt vmcnt(N)+s_barrier keeps 2 A-iters in flight.
// MODE 0: A fp32, no BN (layer 1; LDS exactly 64 KB).
// MODE 1: A bf16, BN+ReLU applied post-LDS-read (BN table in LDS; no in-loop vmem).
template<int MODE, int KC>
__global__ __launch_bounds__(256) void gemm_kernel(const void* __restrict__ Av,
                                                   const bf16_t* __restrict__ Wb,
                                                   const float* __restrict__ sc,
                                                   bf16_t* __restrict__ Cl,
                                                   bf16_t* __restrict__ Cr,
                                                   int M)
{
    constexpr int NK   = KC / 32;
    constexpr int ASZ  = (MODE == 0) ? 16384 : 8192;   // one A buffer
    constexpr int BSZ  = 8192;                         // one B buffer
    constexpr int NBB  = (MODE == 0) ? 2 : 3;
    constexpr int AISS = (MODE == 0) ? 4 : 2;
    constexpr int AKB  = (MODE == 0) ? 128 : 64;       // A bytes per k-iter along row
    constexpr int SCSZ = (MODE == 1) ? 1024 : 0;
    __shared__ __align__(16) unsigned char smem[3 * ASZ + NBB * BSZ + SCSZ];
    unsigned char* Asm = smem;
    unsigned char* Bsm = smem + 3 * ASZ;
    float* scS = (float*)(smem + 3 * ASZ + NBB * BSZ);

    const int t    = threadIdx.x;
    const int m0   = blockIdx.x * 128;
    const int half = blockIdx.y;
    const int wid  = t >> 6;
    const int lane = t & 63;
    const int wm   = (wid >> 1) * 64;
    const int wn   = (wid & 1) * 64;
    const int l16  = lane & 15;
    const int quad = lane >> 4;

    // ---- async-loader sources (XOR swizzle folded into the global side) ----
    const char* aSrc[AISS]; int aDst[AISS];
#pragma unroll
    for (int s = 0; s < AISS; s++) {
        int L = (s * 4 + wid) * 64 + lane;   // 16B-chunk slot; LDS byte = L*16
        int r, c;
        if (MODE == 0) { r = L >> 3; c = (L & 7) ^ (r & 7); }         // 8 chunks/row (f32)
        else           { r = L >> 2; c = (L & 3) ^ ((r >> 1) & 3); }  // 4 chunks/row (bf16)
        int row = m0 + r; if (row > M - 1) row = M - 1;   // clamp; never stored
        if (MODE == 0) aSrc[s] = (const char*)Av + ((size_t)row * KC + (size_t)c * 4) * 4;
        else           aSrc[s] = (const char*)Av + ((size_t)row * KC + (size_t)c * 8) * 2;
        aDst[s] = (s * 4 + wid) * 1024;      // wave-uniform base
    }
    const char* bSrc[2]; int bDst[2];
#pragma unroll
    for (int s = 0; s < 2; s++) {
        int L = (s * 4 + wid) * 64 + lane;
        int r = L >> 2;
        int c = (L & 3) ^ ((r >> 1) & 3);
        bSrc[s] = (const char*)(Wb + (size_t)(half * 128 + r) * KC + c * 8);
        bDst[s] = (s * 4 + wid) * 1024;
    }

    // ---- fragment LDS byte offsets within one buffer (conflict-free phases) ----
    int aOff[4][2], bOff[4];
#pragma unroll
    for (int i = 0; i < 4; i++) {
        int ra = wm + i * 16 + l16;
        if (MODE == 0) {
            aOff[i][0] = ra * 128 + (((2 * quad)     ^ (ra & 7)) * 16);
            aOff[i][1] = ra * 128 + (((2 * quad + 1) ^ (ra & 7)) * 16);
        } else {
            aOff[i][0] = ra * 64 + ((quad ^ ((ra >> 1) & 3)) * 16);
            aOff[i][1] = 0;
        }
        int rb = wn + i * 16 + l16;
        bOff[i] = rb * 64 + ((quad ^ ((rb >> 1) & 3)) * 16);
    }

    if (MODE == 1) {           // BN table -> LDS (keeps K-loop vmcnt-clean)
        scS[t] = sc[t];
        __syncthreads();
    }

    // ---- prologue (FIFO: A0, B0, A1  /  MODE1: A0,B0,A1,B1) ----
#pragma unroll
    for (int s = 0; s < AISS; s++) cp16(aSrc[s], Asm + aDst[s]);
#pragma unroll
    for (int s = 0; s < 2; s++)    cp16(bSrc[s], Bsm + bDst[s]);
#pragma unroll
    for (int s = 0; s < AISS; s++) cp16(aSrc[s] + AKB, Asm + ASZ + aDst[s]);
    if (MODE == 1) {
#pragma unroll
        for (int s = 0; s < 2; s++) cp16(bSrc[s] + 64, Bsm + BSZ + bDst[s]);
    }

    f32x4 acc[4][4] = {};

    for (int it = 0; it < NK; ++it) {
        if (it + 2 < NK) {
            if constexpr (MODE == 0) {
                const size_t kb1 = (size_t)(it + 1) * 64;
                const int bb = (it + 1) & 1;
#pragma unroll
                for (int s = 0; s < 2; s++) cp16(bSrc[s] + kb1, Bsm + bb * BSZ + bDst[s]);
                const size_t ka2 = (size_t)(it + 2) * 128;
                const int ab = (it + 2) % 3;
#pragma unroll
                for (int s = 0; s < 4; s++) cp16(aSrc[s] + ka2, Asm + ab * ASZ + aDst[s]);
                asm volatile("s_waitcnt vmcnt(10)" ::: "memory");
            } else {
                const size_t kb2 = (size_t)(it + 2) * 64;
                const int nb = (it + 2) % 3;
#pragma unroll
                for (int s = 0; s < 2; s++) cp16(aSrc[s] + kb2, Asm + nb * ASZ + aDst[s]);
#pragma unroll
                for (int s = 0; s < 2; s++) cp16(bSrc[s] + kb2, Bsm + nb * BSZ + bDst[s]);
                asm volatile("s_waitcnt vmcnt(8)" ::: "memory");
            }
        } else if (it + 1 < NK) {
            if constexpr (MODE == 0) {
                const size_t kb1 = (size_t)(it + 1) * 64;
                const int bb = (it + 1) & 1;
#pragma unroll
                for (int s = 0; s < 2; s++) cp16(bSrc[s] + kb1, Bsm + bb * BSZ + bDst[s]);
                asm volatile("s_waitcnt vmcnt(6)" ::: "memory");
            } else {
                asm volatile("s_waitcnt vmcnt(4)" ::: "memory");
            }
        } else {
            asm volatile("s_waitcnt vmcnt(0)" ::: "memory");
        }
        asm volatile("s_barrier" ::: "memory");

        const unsigned char* Ab = Asm + (it % 3) * ASZ;
        const unsigned char* Bb = Bsm + ((MODE == 0) ? (it & 1) : (it % 3)) * BSZ;
        bf16x8 af[4], bfr[4];
        if constexpr (MODE == 0) {
#pragma unroll
            for (int i = 0; i < 4; i++) {
                float4 u0 = *(const float4*)(Ab + aOff[i][0]);
                float4 u1 = *(const float4*)(Ab + aOff[i][1]);
                af[i][0] = (bf16_t)u0.x; af[i][1] = (bf16_t)u0.y;
                af[i][2] = (bf16_t)u0.z; af[i][3] = (bf16_t)u0.w;
                af[i][4] = (bf16_t)u1.x; af[i][5] = (bf16_t)u1.y;
                af[i][6] = (bf16_t)u1.z; af[i][7] = (bf16_t)u1.w;
            }
        } else {
            float4 s0 = *(const float4*)&scS[it * 32 + quad * 8];
            float4 s1 = *(const float4*)&scS[it * 32 + quad * 8 + 4];
            float4 h0 = *(const float4*)&scS[HIDC + it * 32 + quad * 8];
            float4 h1 = *(const float4*)&scS[HIDC + it * 32 + quad * 8 + 4];
            float ss[8] = {s0.x, s0.y, s0.z, s0.w, s1.x, s1.y, s1.z, s1.w};
            float hh[8] = {h0.x, h0.y, h0.z, h0.w, h1.x, h1.y, h1.z, h1.w};
#pragma unroll
            for (int i = 0; i < 4; i++) {
                bf16x8 raw = *(const bf16x8*)(Ab + aOff[i][0]);
#pragma unroll
                for (int e = 0; e < 8; e++)
                    af[i][e] = (bf16_t)fmaxf(fmaf((float)raw[e], ss[e], hh[e]), 0.0f);
            }
        }
#pragma unroll
        for (int j = 0; j < 4; j++)
            bfr[j] = *(const bf16x8*)(Bb + bOff[j]);
#pragma unroll
        for (int i = 0; i < 4; i++)
#pragma unroll
            for (int j = 0; j < 4; j++)
                acc[i][j] = mfma_16x16x32_bf16(af[i], bfr[j], acc[i][j]);

        asm volatile("s_barrier" ::: "memory");   // protect bufs reused at it+1's stage
    }

    // C/D layout (m89-verified, validated rounds 1-7)
    bf16_t* C = half ? Cr : Cl;
#pragma unroll
    for (int i = 0; i < 4; i++) {
        int rowb = m0 + wm + i * 16 + quad * 4;
#pragma unroll
        for (int j = 0; j < 4; j++) {
            int colh = wn + j * 16 + l16;
#pragma unroll
            for (int rr = 0; rr < 4; rr++) {
                int row = rowb + rr;
                if (row < M) C[(size_t)row * HIDC + colh] = (bf16_t)acc[i][j][rr];
            }
        }
    }
}

// ---------- fused init: weight converts + zero degi/stats/done ----------
__global__ void init_kernel(const float* __restrict__ W1l, const float* __restrict__ W1r,
                            const float* __restrict__ W2l, const float* __restrict__ W2r,
                            const float* __restrict__ W3l, const float* __restrict__ W3r,
                            bf16_t* __restrict__ Wb1, bf16_t* __restrict__ Wb2,
                            bf16_t* __restrict__ Wb3,
                            int* __restrict__ degi, float* __restrict__ stats,
                            int* __restrict__ done)
{
    const int NW1 = 128 * IN_DIMC;   // 98304
    const int NW2 = 128 * HIDC;      // 16384
    const int NS  = 3 * NREP * 256;  // 49152
    int j = blockIdx.x * blockDim.x + threadIdx.x;
    if (j < 2 * NW1) { Wb1[j] = (bf16_t)((j < NW1) ? W1l[j] : W1r[j - NW1]); return; }
    j -= 2 * NW1;
    if (j < 2 * NW2) { Wb2[j] = (bf16_t)((j < NW2) ? W2l[j] : W2r[j - NW2]); return; }
    j -= 2 * NW2;
    if (j < 2 * NW2) { Wb3[j] = (bf16_t)((j < NW2) ? W3l[j] : W3r[j - NW2]); return; }
    j -= 2 * NW2;
    if (j < NS) { stats[j] = 0.0f; return; }
    j -= NS;
    if (j < N_NODESC) { degi[j] = 0; return; }
    j -= N_NODESC;
    if (j < 16) done[j] = 0;
}

// ---------- CSR build ----------
__global__ void degi_kernel(const int* __restrict__ ei, int* __restrict__ degi) {
    int e = blockIdx.x * blockDim.x + threadIdx.x;
    if (e < N_EDGESC) atomicAdd(&degi[ei[N_EDGESC + e]], 1);
}

__global__ __launch_bounds__(256) void scan1_kernel(const int* __restrict__ degi,
                                                    int* __restrict__ local,
                                                    int* __restrict__ partials)
{
    __shared__ int tmp[256];
    const int t = threadIdx.x;
    const int i = blockIdx.x * 256 + t;
    int v = (i < N_NODESC) ? degi[i] : 0;
    tmp[t] = v;
    __syncthreads();
    for (int off = 1; off < 256; off <<= 1) {
        int u = (t >= off) ? tmp[t - off] : 0;
        __syncthreads();
        tmp[t] += u;
        __syncthreads();
    }
    if (i < N_NODESC) local[i] = tmp[t] - v;
    if (t == 255) partials[blockIdx.x] = tmp[255];
}

__global__ __launch_bounds__(256) void scan2_kernel(int* __restrict__ partials)
{
    __shared__ int tmp[256];
    const int t = threadIdx.x;
    int v = (t < SCAN_NB) ? partials[t] : 0;
    tmp[t] = v;
    __syncthreads();
    for (int off = 1; off < 256; off <<= 1) {
        int u = (t >= off) ? tmp[t - off] : 0;
        __syncthreads();
        tmp[t] += u;
        __syncthreads();
    }
    if (t < SCAN_NB) partials[t] = tmp[t] - v;
}

__global__ __launch_bounds__(256) void scan3_kernel(const int* __restrict__ local,
                                                    const int* __restrict__ partials,
                                                    int* __restrict__ rowptr,
                                                    int* __restrict__ cursor)
{
    const int i = blockIdx.x * 256 + threadIdx.x;
    if (i < N_NODESC) {
        int r = local[i] + partials[blockIdx.x];
        rowptr[i] = r;
        cursor[i] = r;
    }
    if (i == 0) rowptr[N_NODESC] = N_EDGESC;
}

__global__ void fill_kernel(const int* __restrict__ ei, int* __restrict__ cursor,
                            int* __restrict__ col) {
    int e = blockIdx.x * blockDim.x + threadIdx.x;
    if (e >= N_EDGESC) return;
    int d = ei[N_EDGESC + e];
    int pos = atomicAdd(&cursor[d], 1);
    col[pos] = ei[e];
}

// ---------- fused CSR-gather mean-agg + bias + Pr + BN stats + last-block finalize ----------
__global__ __launch_bounds__(128) void agg_combine_kernel(const int* __restrict__ rowptr,
                                                          const int* __restrict__ col,
                                                          const bf16_t* __restrict__ Plb,
                                                          const bf16_t* __restrict__ Prb,
                                                          const float* __restrict__ bias,
                                                          bf16_t* __restrict__ Hb,
                                                          float* __restrict__ stats,
                                                          const float* __restrict__ g,
                                                          const float* __restrict__ be,
                                                          float* __restrict__ sc,
                                                          int* __restrict__ done, int M)
{
    const int lane = threadIdx.x & 63;
    const int wv   = threadIdx.x >> 6;
    const int c0   = lane * 2;
    const float b0 = bias[c0], b1v = bias[c0 + 1];
    float s0 = 0.f, s1 = 0.f, q0 = 0.f, q1 = 0.f;
    const int n0 = blockIdx.x * NB_AGG + wv * (NB_AGG / 2);
    for (int rr = 0; rr < NB_AGG / 2; rr++) {
        int n = n0 + rr;
        if (n >= M) break;
        int lo = rowptr[n], hi = rowptr[n + 1];
        float a0 = 0.f, a1 = 0.f;
        for (int e = lo; e < hi; e += 8) {
            int rem = hi - e;
            int idx[8];
#pragma unroll
            for (int j = 0; j < 8; j++) {
                int ee = e + j; if (ee > hi - 1) ee = hi - 1;
                idx[j] = col[ee];                 // broadcast loads
            }
            bf16x2 v[8];
#pragma unroll
            for (int j = 0; j < 8; j++)
                v[j] = *(const bf16x2*)&Plb[(size_t)idx[j] * HIDC + c0];  // 8 in flight
#pragma unroll
            for (int j = 0; j < 8; j++)
                if (j < rem) { a0 += (float)v[j][0]; a1 += (float)v[j][1]; }
        }
        int d = hi - lo;
        float inv = 1.0f / (float)(d > 0 ? d : 1);
        bf16x2 pr = *(const bf16x2*)&Prb[(size_t)n * HIDC + c0];
        float pre0 = fmaf(a0, inv, b0) + (float)pr[0];
        float pre1 = fmaf(a1, inv, b1v) + (float)pr[1];
        bf16x2 hv; hv[0] = (bf16_t)pre0; hv[1] = (bf16_t)pre1;
        *(bf16x2*)&Hb[(size_t)n * HIDC + c0] = hv;
        s0 += pre0; s1 += pre1; q0 += pre0 * pre0; q1 += pre1 * pre1;
    }
    const int rep = (blockIdx.x * 2 + wv) & (NREP - 1);
    atomicAdd(&stats[rep * 256 + c0], s0);
    atomicAdd(&stats[rep * 256 + c0 + 1], s1);
    atomicAdd(&stats[rep * 256 + HIDC + c0], q0);
    atomicAdd(&stats[rep * 256 + HIDC + c0 + 1], q1);

    // last block computes BN scale/shift (replaces a separate finalize dispatch)
    __threadfence();
    __syncthreads();
    __shared__ int lastv;
    if (threadIdx.x == 0) lastv = atomicAdd(done, 1);
    __syncthreads();
    if (lastv == (int)gridDim.x - 1) {
        __threadfence();
        int c = threadIdx.x;   // 0..127
        float sum = 0.f, sumsq = 0.f;
        for (int r = 0; r < NREP; r++) {
            sum   += __hip_atomic_load(&stats[r * 256 + c], __ATOMIC_RELAXED, __HIP_MEMORY_SCOPE_AGENT);
            sumsq += __hip_atomic_load(&stats[r * 256 + HIDC + c], __ATOMIC_RELAXED, __HIP_MEMORY_SCOPE_AGENT);
        }
        float invM = 1.0f / (float)M;
        float mean = sum * invM;
        float var  = sumsq * invM - mean * mean;
        float s = rsqrtf(var + BN_EPSC) * g[c];
        sc[c] = s;
        sc[HIDC + c] = be[c] - mean * s;
    }
}

// ---------- fused pool (BN3) + linear head ----------
__global__ __launch_bounds__(128) void poolhead_kernel(const bf16_t* __restrict__ Hb,
                                                       const float* __restrict__ sc,
                                                       const int* __restrict__ batch,
                                                       const float* __restrict__ Wlin,
                                                       const float* __restrict__ blin,
                                                       float* __restrict__ out, int M)
{
    __shared__ float sp[HIDC];
    int gph = blockIdx.x;
    int c   = threadIdx.x;
    float s = sc[c], h = sc[HIDC + c];
    int lo = 0, hi = M;
    while (lo < hi) { int m = (lo + hi) >> 1; if (batch[m] < gph) lo = m + 1; else hi = m; }
    int lo2 = lo, hi2 = M;
    while (lo2 < hi2) { int m = (lo2 + hi2) >> 1; if (batch[m] < gph + 1) lo2 = m + 1; else hi2 = m; }
    float mx = -INFINITY;
    for (int rr = lo; rr < lo2; rr++)
        mx = fmaxf(mx, fmaf((float)Hb[(size_t)rr * HIDC + c], s, h));
    sp[c] = mx;
    __syncthreads();
    if (c < NCLSC) {
        float acc = blin[c];
        for (int k = 0; k < HIDC; k++) acc += sp[k] * Wlin[c * HIDC + k];
        out[gph * NCLSC + c] = acc;
    }
}

extern "C" void kernel_launch(void* const* d_in, const int* in_sizes, int n_in,
                              void* d_out, int out_size, void* d_ws, size_t ws_size,
                              hipStream_t stream)
{
    const float* x     = (const float*)d_in[0];
    const int*   ei    = (const int*)d_in[1];
    const int*   batch = (const int*)d_in[2];
    const float* W1l = (const float*)d_in[3];
    const float* b1  = (const float*)d_in[4];
    const float* W1r = (const float*)d_in[5];
    const float* g1  = (const float*)d_in[6];
    const float* be1 = (const float*)d_in[7];
    const float* W2l = (const float*)d_in[8];
    const float* b2  = (const float*)d_in[9];
    const float* W2r = (const float*)d_in[10];
    const float* g2  = (const float*)d_in[11];
    const float* be2 = (const float*)d_in[12];
    const float* W3l = (const float*)d_in[13];
    const float* b3  = (const float*)d_in[14];
    const float* W3r = (const float*)d_in[15];
    const float* g3  = (const float*)d_in[16];
    const float* be3 = (const float*)d_in[17];
    const float* Wlin = (const float*)d_in[18];
    const float* blin = (const float*)d_in[19];

    const int M = N_NODESC;

    // workspace carve (16B aligned)
    char* w = (char*)d_ws;
    bf16_t* Plb  = (bf16_t*)w;  w += (size_t)M * HIDC * 2;
    bf16_t* Prb  = (bf16_t*)w;  w += (size_t)M * HIDC * 2;
    bf16_t* Hb   = (bf16_t*)w;  w += (size_t)M * HIDC * 2;
    bf16_t* Wb1  = (bf16_t*)w;  w += (size_t)256 * IN_DIMC * 2;
    bf16_t* Wb2  = (bf16_t*)w;  w += (size_t)256 * HIDC * 2;
    bf16_t* Wb3  = (bf16_t*)w;  w += (size_t)256 * HIDC * 2;
    int*   rowptr= (int*)w;     w += (size_t)(M + 16) * 4;
    int*   col   = (int*)w;     w += (size_t)N_EDGESC * 4;
    int*   cursor= (int*)w;     w += (size_t)M * 4;
    int*   degi  = (int*)w;     w += (size_t)M * 4;
    int*   slocal= (int*)w;     w += (size_t)M * 4;
    int*   spart = (int*)w;     w += 256 * 4;
    float* stats = (float*)w;   w += (size_t)3 * NREP * 256 * 4;   // 192 KB, 3 layers
    float* sc    = (float*)w;   w += 3 * 256 * 4;
    int*   done  = (int*)w;     w += 16 * 4;

    float* stats1 = stats;
    float* stats2 = stats + NREP * 256;
    float* stats3 = stats + 2 * NREP * 256;
    float* sc1 = sc, *sc2 = sc + 256, *sc3 = sc + 512;

    const dim3 gemm_grid((M + 127) / 128, 2);
    const int agg_blocks = (M + NB_AGG - 1) / NB_AGG;
    const int init_total = 2 * 128 * IN_DIMC + 4 * 128 * HIDC + 3 * NREP * 256 + M + 16;

    // ---- init (weights + zeros, one dispatch) ----
    init_kernel<<<(init_total + 255) / 256, 256, 0, stream>>>(W1l, W1r, W2l, W2r, W3l, W3r,
                                                              Wb1, Wb2, Wb3, degi, stats, done);
    // ---- CSR build ----
    degi_kernel<<<(N_EDGESC + 255) / 256, 256, 0, stream>>>(ei, degi);
    scan1_kernel<<<SCAN_NB, 256, 0, stream>>>(degi, slocal, spart);
    scan2_kernel<<<1, 256, 0, stream>>>(spart);
    scan3_kernel<<<SCAN_NB, 256, 0, stream>>>(slocal, spart, rowptr, cursor);
    fill_kernel<<<(N_EDGESC + 255) / 256, 256, 0, stream>>>(ei, cursor, col);

    // ---- layer 1 (K=768, A=x fp32) ----
    gemm_kernel<0, IN_DIMC><<<gemm_grid, 256, 0, stream>>>(x, Wb1, nullptr, Plb, Prb, M);
    agg_combine_kernel<<<agg_blocks, 128, 0, stream>>>(rowptr, col, Plb, Prb, b1, Hb,
                                                       stats1, g1, be1, sc1, done + 0, M);
    // ---- layer 2 (K=128, BN1+ReLU fused) ----
    gemm_kernel<1, HIDC><<<gemm_grid, 256, 0, stream>>>(Hb, Wb2, sc1, Plb, Prb, M);
    agg_combine_kernel<<<agg_blocks, 128, 0, stream>>>(rowptr, col, Plb, Prb, b2, Hb,
                                                       stats2, g2, be2, sc2, done + 1, M);
    // ---- layer 3 (K=128, BN2+ReLU fused) ----
    gemm_kernel<1, HIDC><<<gemm_grid, 256, 0, stream>>>(Hb, Wb3, sc2, Plb, Prb, M);
    agg_combine_kernel<<<agg_blocks, 128, 0, stream>>>(rowptr, col, Plb, Prb, b3, Hb,
                                                       stats3, g3, be3, sc3, done + 2, M);
    // ---- pool (BN3 fused) + head ----
    poolhead_kernel<<<N_GRAPHSC, 128, 0, stream>>>(Hb, sc3, batch, Wlin, blin, (float*)d_out, M);
}

// Round 10
// 586.957 us; speedup vs baseline: 2.2724x; 2.2724x over previous
//
#include <hip/hip_runtime.h>

#define N_NODESC 50000
#define N_EDGESC 400000
#define N_GRAPHSC 128
#define IN_DIMC 768
#define HIDC 128
#define NCLSC 11
#define BN_EPSC 1e-5f
#define NB_AGG 8
#define NREP 64
#define SCAN_NB ((N_NODESC + 255) / 256)

typedef __bf16 bf16_t;
typedef __bf16 bf16x2 __attribute__((ext_vector_type(2)));
typedef __bf16 bf16x8 __attribute__((ext_vector_type(8)));
typedef float f32x4 __attribute__((ext_vector_type(4)));

typedef __attribute__((address_space(1))) void glb_void;
typedef __attribute__((address_space(3))) void lds_void;

__device__ __forceinline__ void cp16(const void* g, void* l) {
    // async global->LDS, 16B/lane; LDS dst = wave-uniform base + lane*16
    __builtin_amdgcn_global_load_lds((glb_void*)g, (lds_void*)l, 16, 0, 0);
}

__device__ __forceinline__ f32x4 mfma_16x16x32_bf16(bf16x8 a, bf16x8 b, f32x4 c) {
    return __builtin_amdgcn_mfma_f32_16x16x32_bf16(a, b, c, 0, 0, 0);
}

// [Cl|Cr] = BN?(A)[M,K] @ Wb^T, Wb [256,K] bf16. Tile 128x128xBK32, grid (M/128, 2).
// Depth-2 async pipeline: A triple-buffered, B double (MODE0) / triple (MODE1);
// raw s_waitcnt vmcnt(N)+s_barrier keeps 2 A-iters in flight across the barrier.
// MODE 0: A fp32, no BN (layer 1; LDS exactly 64 KB).
// MODE 1: A bf16, BN+ReLU applied post-LDS-read (BN table in LDS; no in-loop vmem).
template<int MODE, int KC>
__global__ __launch_bounds__(256) void gemm_kernel(const void* __restrict__ Av,
                                                   const bf16_t* __restrict__ Wb,
                                                   const float* __restrict__ sc,
                                                   bf16_t* __restrict__ Cl,
                                                   bf16_t* __restrict__ Cr,
                                                   int M)
{
    constexpr int NK   = KC / 32;
    constexpr int ASZ  = (MODE == 0) ? 16384 : 8192;   // one A buffer
    constexpr int BSZ  = 8192;                         // one B buffer
    constexpr int NBB  = (MODE == 0) ? 2 : 3;
    constexpr int AISS = (MODE == 0) ? 4 : 2;
    constexpr int AKB  = (MODE == 0) ? 128 : 64;       // A bytes per k-iter along row
    constexpr int SCSZ = (MODE == 1) ? 1024 : 0;
    __shared__ __align__(16) unsigned char smem[3 * ASZ + NBB * BSZ + SCSZ];
    unsigned char* Asm = smem;
    unsigned char* Bsm = smem + 3 * ASZ;
    float* scS = (float*)(smem + 3 * ASZ + NBB * BSZ);

    const int t    = threadIdx.x;
    const int m0   = blockIdx.x * 128;
    const int half = blockIdx.y;
    const int wid  = t >> 6;
    const int lane = t & 63;
    const int wm   = (wid >> 1) * 64;
    const int wn   = (wid & 1) * 64;
    const int l16  = lane & 15;
    const int quad = lane >> 4;

    // ---- async-loader sources (XOR swizzle folded into the global side) ----
    const char* aSrc[AISS]; int aDst[AISS];
#pragma unroll
    for (int s = 0; s < AISS; s++) {
        int L = (s * 4 + wid) * 64 + lane;   // 16B-chunk slot; LDS byte = L*16
        int r, c;
        if (MODE == 0) { r = L >> 3; c = (L & 7) ^ (r & 7); }         // 8 chunks/row (f32)
        else           { r = L >> 2; c = (L & 3) ^ ((r >> 1) & 3); }  // 4 chunks/row (bf16)
        int row = m0 + r; if (row > M - 1) row = M - 1;   // clamp; never stored
        if (MODE == 0) aSrc[s] = (const char*)Av + ((size_t)row * KC + (size_t)c * 4) * 4;
        else           aSrc[s] = (const char*)Av + ((size_t)row * KC + (size_t)c * 8) * 2;
        aDst[s] = (s * 4 + wid) * 1024;      // wave-uniform base
    }
    const char* bSrc[2]; int bDst[2];
#pragma unroll
    for (int s = 0; s < 2; s++) {
        int L = (s * 4 + wid) * 64 + lane;
        int r = L >> 2;
        int c = (L & 3) ^ ((r >> 1) & 3);
        bSrc[s] = (const char*)(Wb + (size_t)(half * 128 + r) * KC + c * 8);
        bDst[s] = (s * 4 + wid) * 1024;
    }

    // ---- fragment LDS byte offsets within one buffer (conflict-free phases) ----
    int aOff[4][2], bOff[4];
#pragma unroll
    for (int i = 0; i < 4; i++) {
        int ra = wm + i * 16 + l16;
        if (MODE == 0) {
            aOff[i][0] = ra * 128 + (((2 * quad)     ^ (ra & 7)) * 16);
            aOff[i][1] = ra * 128 + (((2 * quad + 1) ^ (ra & 7)) * 16);
        } else {
            aOff[i][0] = ra * 64 + ((quad ^ ((ra >> 1) & 3)) * 16);
            aOff[i][1] = 0;
        }
        int rb = wn + i * 16 + l16;
        bOff[i] = rb * 64 + ((quad ^ ((rb >> 1) & 3)) * 16);
    }

    if (MODE == 1) {           // BN table -> LDS (keeps K-loop vmcnt-clean)
        scS[t] = sc[t];
        __syncthreads();
    }

    // ---- prologue (FIFO: A0, B0, A1  /  MODE1: A0,B0,A1,B1) ----
#pragma unroll
    for (int s = 0; s < AISS; s++) cp16(aSrc[s], Asm + aDst[s]);
#pragma unroll
    for (int s = 0; s < 2; s++)    cp16(bSrc[s], Bsm + bDst[s]);
#pragma unroll
    for (int s = 0; s < AISS; s++) cp16(aSrc[s] + AKB, Asm + ASZ + aDst[s]);
    if (MODE == 1) {
#pragma unroll
        for (int s = 0; s < 2; s++) cp16(bSrc[s] + 64, Bsm + BSZ + bDst[s]);
    }

    f32x4 acc[4][4] = {};

    for (int it = 0; it < NK; ++it) {
        if (it + 2 < NK) {
            if constexpr (MODE == 0) {
                const size_t kb1 = (size_t)(it + 1) * 64;
                const int bb = (it + 1) & 1;
#pragma unroll
                for (int s = 0; s < 2; s++) cp16(bSrc[s] + kb1, Bsm + bb * BSZ + bDst[s]);
                const size_t ka2 = (size_t)(it + 2) * 128;
                const int ab = (it + 2) % 3;
#pragma unroll
                for (int s = 0; s < 4; s++) cp16(aSrc[s] + ka2, Asm + ab * ASZ + aDst[s]);
                asm volatile("s_waitcnt vmcnt(10)" ::: "memory");
            } else {
                const size_t kb2 = (size_t)(it + 2) * 64;
                const int nb = (it + 2) % 3;
#pragma unroll
                for (int s = 0; s < 2; s++) cp16(aSrc[s] + kb2, Asm + nb * ASZ + aDst[s]);
#pragma unroll
                for (int s = 0; s < 2; s++) cp16(bSrc[s] + kb2, Bsm + nb * BSZ + bDst[s]);
                asm volatile("s_waitcnt vmcnt(8)" ::: "memory");
            }
        } else if (it + 1 < NK) {
            if constexpr (MODE == 0) {
                const size_t kb1 = (size_t)(it + 1) * 64;
                const int bb = (it + 1) & 1;
#pragma unroll
                for (int s = 0; s < 2; s++) cp16(bSrc[s] + kb1, Bsm + bb * BSZ + bDst[s]);
                asm volatile("s_waitcnt vmcnt(6)" ::: "memory");
            } else {
                asm volatile("s_waitcnt vmcnt(4)" ::: "memory");
            }
        } else {
            asm volatile("s_waitcnt vmcnt(0)" ::: "memory");
        }
        asm volatile("s_barrier" ::: "memory");

        const unsigned char* Ab = Asm + (it % 3) * ASZ;
        const unsigned char* Bb = Bsm + ((MODE == 0) ? (it & 1) : (it % 3)) * BSZ;
        bf16x8 af[4], bfr[4];
        if constexpr (MODE == 0) {
#pragma unroll
            for (int i = 0; i < 4; i++) {
                float4 u0 = *(const float4*)(Ab + aOff[i][0]);
                float4 u1 = *(const float4*)(Ab + aOff[i][1]);
                af[i][0] = (bf16_t)u0.x; af[i][1] = (bf16_t)u0.y;
                af[i][2] = (bf16_t)u0.z; af[i][3] = (bf16_t)u0.w;
                af[i][4] = (bf16_t)u1.x; af[i][5] = (bf16_t)u1.y;
                af[i][6] = (bf16_t)u1.z; af[i][7] = (bf16_t)u1.w;
            }
        } else {
            float4 s0 = *(const float4*)&scS[it * 32 + quad * 8];
            float4 s1 = *(const float4*)&scS[it * 32 + quad * 8 + 4];
            float4 h0 = *(const float4*)&scS[HIDC + it * 32 + quad * 8];
            float4 h1 = *(const float4*)&scS[HIDC + it * 32 + quad * 8 + 4];
            float ss[8] = {s0.x, s0.y, s0.z, s0.w, s1.x, s1.y, s1.z, s1.w};
            float hh[8] = {h0.x, h0.y, h0.z, h0.w, h1.x, h1.y, h1.z, h1.w};
#pragma unroll
            for (int i = 0; i < 4; i++) {
                bf16x8 raw = *(const bf16x8*)(Ab + aOff[i][0]);
#pragma unroll
                for (int e = 0; e < 8; e++)
                    af[i][e] = (bf16_t)fmaxf(fmaf((float)raw[e], ss[e], hh[e]), 0.0f);
            }
        }
#pragma unroll
        for (int j = 0; j < 4; j++)
            bfr[j] = *(const bf16x8*)(Bb + bOff[j]);
#pragma unroll
        for (int i = 0; i < 4; i++)
#pragma unroll
            for (int j = 0; j < 4; j++)
                acc[i][j] = mfma_16x16x32_bf16(af[i], bfr[j], acc[i][j]);

        asm volatile("s_barrier" ::: "memory");   // protect bufs reused at it+1's stage
    }

    // C/D layout (m89-verified, validated rounds 1-8)
    bf16_t* C = half ? Cr : Cl;
#pragma unroll
    for (int i = 0; i < 4; i++) {
        int rowb = m0 + wm + i * 16 + quad * 4;
#pragma unroll
        for (int j = 0; j < 4; j++) {
            int colh = wn + j * 16 + l16;
#pragma unroll
            for (int rr = 0; rr < 4; rr++) {
                int row = rowb + rr;
                if (row < M) C[(size_t)row * HIDC + colh] = (bf16_t)acc[i][j][rr];
            }
        }
    }
}

// ---------- fused init: weight converts + zero degi/stats ----------
__global__ void init_kernel(const float* __restrict__ W1l, const float* __restrict__ W1r,
                            const float* __restrict__ W2l, const float* __restrict__ W2r,
                            const float* __restrict__ W3l, const float* __restrict__ W3r,
                            bf16_t* __restrict__ Wb1, bf16_t* __restrict__ Wb2,
                            bf16_t* __restrict__ Wb3,
                            int* __restrict__ degi, float* __restrict__ stats)
{
    const int NW1 = 128 * IN_DIMC;   // 98304
    const int NW2 = 128 * HIDC;      // 16384
    const int NS  = 3 * NREP * 256;  // 49152
    int j = blockIdx.x * blockDim.x + threadIdx.x;
    if (j < 2 * NW1) { Wb1[j] = (bf16_t)((j < NW1) ? W1l[j] : W1r[j - NW1]); return; }
    j -= 2 * NW1;
    if (j < 2 * NW2) { Wb2[j] = (bf16_t)((j < NW2) ? W2l[j] : W2r[j - NW2]); return; }
    j -= 2 * NW2;
    if (j < 2 * NW2) { Wb3[j] = (bf16_t)((j < NW2) ? W3l[j] : W3r[j - NW2]); return; }
    j -= 2 * NW2;
    if (j < NS) { stats[j] = 0.0f; return; }
    j -= NS;
    if (j < N_NODESC) degi[j] = 0;
}

// ---------- CSR build ----------
__global__ void degi_kernel(const int* __restrict__ ei, int* __restrict__ degi) {
    int e = blockIdx.x * blockDim.x + threadIdx.x;
    if (e < N_EDGESC) atomicAdd(&degi[ei[N_EDGESC + e]], 1);
}

__global__ __launch_bounds__(256) void scan1_kernel(const int* __restrict__ degi,
                                                    int* __restrict__ local,
                                                    int* __restrict__ partials)
{
    __shared__ int tmp[256];
    const int t = threadIdx.x;
    const int i = blockIdx.x * 256 + t;
    int v = (i < N_NODESC) ? degi[i] : 0;
    tmp[t] = v;
    __syncthreads();
    for (int off = 1; off < 256; off <<= 1) {
        int u = (t >= off) ? tmp[t - off] : 0;
        __syncthreads();
        tmp[t] += u;
        __syncthreads();
    }
    if (i < N_NODESC) local[i] = tmp[t] - v;
    if (t == 255) partials[blockIdx.x] = tmp[255];
}

__global__ __launch_bounds__(256) void scan2_kernel(int* __restrict__ partials)
{
    __shared__ int tmp[256];
    const int t = threadIdx.x;
    int v = (t < SCAN_NB) ? partials[t] : 0;
    tmp[t] = v;
    __syncthreads();
    for (int off = 1; off < 256; off <<= 1) {
        int u = (t >= off) ? tmp[t - off] : 0;
        __syncthreads();
        tmp[t] += u;
        __syncthreads();
    }
    if (t < SCAN_NB) partials[t] = tmp[t] - v;
}

__global__ __launch_bounds__(256) void scan3_kernel(const int* __restrict__ local,
                                                    const int* __restrict__ partials,
                                                    int* __restrict__ rowptr,
                                                    int* __restrict__ cursor)
{
    const int i = blockIdx.x * 256 + threadIdx.x;
    if (i < N_NODESC) {
        int r = local[i] + partials[blockIdx.x];
        rowptr[i] = r;
        cursor[i] = r;
    }
    if (i == 0) rowptr[N_NODESC] = N_EDGESC;
}

__global__ void fill_kernel(const int* __restrict__ ei, int* __restrict__ cursor,
                            int* __restrict__ col) {
    int e = blockIdx.x * blockDim.x + threadIdx.x;
    if (e >= N_EDGESC) return;
    int d = ei[N_EDGESC + e];
    int pos = atomicAdd(&cursor[d], 1);
    col[pos] = ei[e];
}

// ---------- fused CSR-gather mean-agg + bias + Pr + BN partial sums ----------
// One WAVE covers a full 128-channel row via bf16x2 lanes; 2 waves/block on
// disjoint row sets; 8-way edge unroll; stats -> per-wave replica slot.
// NO device-scope fences here (R8 lesson: per-block fences on 8-XCD CDNA
// force L2 writebacks and cost ~250 us/layer).
__global__ __launch_bounds__(128) void agg_combine_kernel(const int* __restrict__ rowptr,
                                                          const int* __restrict__ col,
                                                          const bf16_t* __restrict__ Plb,
                                                          const bf16_t* __restrict__ Prb,
                                                          const float* __restrict__ bias,
                                                          bf16_t* __restrict__ Hb,
                                                          float* __restrict__ stats, int M)
{
    const int lane = threadIdx.x & 63;
    const int wv   = threadIdx.x >> 6;
    const int c0   = lane * 2;
    const float b0 = bias[c0], b1v = bias[c0 + 1];
    float s0 = 0.f, s1 = 0.f, q0 = 0.f, q1 = 0.f;
    const int n0 = blockIdx.x * NB_AGG + wv * (NB_AGG / 2);
    for (int rr = 0; rr < NB_AGG / 2; rr++) {
        int n = n0 + rr;
        if (n >= M) break;
        int lo = rowptr[n], hi = rowptr[n + 1];
        float a0 = 0.f, a1 = 0.f;
        for (int e = lo; e < hi; e += 8) {
            int rem = hi - e;
            int idx[8];
#pragma unroll
            for (int j = 0; j < 8; j++) {
                int ee = e + j; if (ee > hi - 1) ee = hi - 1;
                idx[j] = col[ee];                 // broadcast loads
            }
            bf16x2 v[8];
#pragma unroll
            for (int j = 0; j < 8; j++)
                v[j] = *(const bf16x2*)&Plb[(size_t)idx[j] * HIDC + c0];  // 8 in flight
#pragma unroll
            for (int j = 0; j < 8; j++)
                if (j < rem) { a0 += (float)v[j][0]; a1 += (float)v[j][1]; }
        }
        int d = hi - lo;
        float inv = 1.0f / (float)(d > 0 ? d : 1);
        bf16x2 pr = *(const bf16x2*)&Prb[(size_t)n * HIDC + c0];
        float pre0 = fmaf(a0, inv, b0) + (float)pr[0];
        float pre1 = fmaf(a1, inv, b1v) + (float)pr[1];
        bf16x2 hv; hv[0] = (bf16_t)pre0; hv[1] = (bf16_t)pre1;
        *(bf16x2*)&Hb[(size_t)n * HIDC + c0] = hv;
        s0 += pre0; s1 += pre1; q0 += pre0 * pre0; q1 += pre1 * pre1;
    }
    const int rep = (blockIdx.x * 2 + wv) & (NREP - 1);
    atomicAdd(&stats[rep * 256 + c0], s0);
    atomicAdd(&stats[rep * 256 + c0 + 1], s1);
    atomicAdd(&stats[rep * 256 + HIDC + c0], q0);
    atomicAdd(&stats[rep * 256 + HIDC + c0 + 1], q1);
}

// fold NREP replicas; stats -> per-channel scale/shift:  y = x*scale + shift
__global__ __launch_bounds__(128) void finalize_kernel(const float* __restrict__ stats,
                                                       const float* __restrict__ g,
                                                       const float* __restrict__ be,
                                                       float* __restrict__ sc, int M)
{
    int c = threadIdx.x;
    float sum = 0.f, sumsq = 0.f;
    for (int r = 0; r < NREP; r++) {
        sum   += stats[r * 256 + c];
        sumsq += stats[r * 256 + HIDC + c];
    }
    float invM = 1.0f / (float)M;
    float mean = sum * invM;
    float var  = sumsq * invM - mean * mean;
    float s = rsqrtf(var + BN_EPSC) * g[c];
    sc[c] = s;
    sc[HIDC + c] = be[c] - mean * s;
}

// ---------- fused pool (BN3) + linear head ----------
__global__ __launch_bounds__(128) void poolhead_kernel(const bf16_t* __restrict__ Hb,
                                                       const float* __restrict__ sc,
                                                       const int* __restrict__ batch,
                                                       const float* __restrict__ Wlin,
                                                       const float* __restrict__ blin,
                                                       float* __restrict__ out, int M)
{
    __shared__ float sp[HIDC];
    int gph = blockIdx.x;
    int c   = threadIdx.x;
    float s = sc[c], h = sc[HIDC + c];
    int lo = 0, hi = M;
    while (lo < hi) { int m = (lo + hi) >> 1; if (batch[m] < gph) lo = m + 1; else hi = m; }
    int lo2 = lo, hi2 = M;
    while (lo2 < hi2) { int m = (lo2 + hi2) >> 1; if (batch[m] < gph + 1) lo2 = m + 1; else hi2 = m; }
    float mx = -INFINITY;
    for (int rr = lo; rr < lo2; rr++)
        mx = fmaxf(mx, fmaf((float)Hb[(size_t)rr * HIDC + c], s, h));
    sp[c] = mx;
    __syncthreads();
    if (c < NCLSC) {
        float acc = blin[c];
        for (int k = 0; k < HIDC; k++) acc += sp[k] * Wlin[c * HIDC + k];
        out[gph * NCLSC + c] = acc;
    }
}

extern "C" void kernel_launch(void* const* d_in, const int* in_sizes, int n_in,
                              void* d_out, int out_size, void* d_ws, size_t ws_size,
                              hipStream_t stream)
{
    const float* x     = (const float*)d_in[0];
    const int*   ei    = (const int*)d_in[1];
    const int*   batch = (const int*)d_in[2];
    const float* W1l = (const float*)d_in[3];
    const float* b1  = (const float*)d_in[4];
    const float* W1r = (const float*)d_in[5];
    const float* g1  = (const float*)d_in[6];
    const float* be1 = (const float*)d_in[7];
    const float* W2l = (const float*)d_in[8];
    const float* b2  = (const float*)d_in[9];
    const float* W2r = (const float*)d_in[10];
    const float* g2  = (const float*)d_in[11];
    const float* be2 = (const float*)d_in[12];
    const float* W3l = (const float*)d_in[13];
    const float* b3  = (const float*)d_in[14];
    const float* W3r = (const float*)d_in[15];
    const float* g3  = (const float*)d_in[16];
    const float* be3 = (const float*)d_in[17];
    const float* Wlin = (const float*)d_in[18];
    const float* blin = (const float*)d_in[19];

    const int M = N_NODESC;

    // workspace carve (16B aligned)
    char* w = (char*)d_ws;
    bf16_t* Plb  = (bf16_t*)w;  w += (size_t)M * HIDC * 2;
    bf16_t* Prb  = (bf16_t*)w;  w += (size_t)M * HIDC * 2;
    bf16_t* Hb   = (bf16_t*)w;  w += (size_t)M * HIDC * 2;
    bf16_t* Wb1  = (bf16_t*)w;  w += (size_t)256 * IN_DIMC * 2;
    bf16_t* Wb2  = (bf16_t*)w;  w += (size_t)256 * HIDC * 2;
    bf16_t* Wb3  = (bf16_t*)w;  w += (size_t)256 * HIDC * 2;
    int*   rowptr= (int*)w;     w += (size_t)(M + 16) * 4;
    int*   col   = (int*)w;     w += (size_t)N_EDGESC * 4;
    int*   cursor= (int*)w;     w += (size_t)M * 4;
    int*   degi  = (int*)w;     w += (size_t)M * 4;
    int*   slocal= (int*)w;     w += (size_t)M * 4;
    int*   spart = (int*)w;     w += 256 * 4;
    float* stats = (float*)w;   w += (size_t)3 * NREP * 256 * 4;   // 3 layers, zeroed in init
    float* sc    = (float*)w;   w += 3 * 256 * 4;

    float* stats1 = stats;
    float* stats2 = stats + NREP * 256;
    float* stats3 = stats + 2 * NREP * 256;
    float* sc1 = sc, *sc2 = sc + 256, *sc3 = sc + 512;

    const dim3 gemm_grid((M + 127) / 128, 2);
    const int agg_blocks = (M + NB_AGG - 1) / NB_AGG;
    const int init_total = 2 * 128 * IN_DIMC + 4 * 128 * HIDC + 3 * NREP * 256 + M;

    // ---- init (weights + zeros, one dispatch) ----
    init_kernel<<<(init_total + 255) / 256, 256, 0, stream>>>(W1l, W1r, W2l, W2r, W3l, W3r,
                                                              Wb1, Wb2, Wb3, degi, stats);
    // ---- CSR build ----
    degi_kernel<<<(N_EDGESC + 255) / 256, 256, 0, stream>>>(ei, degi);
    scan1_kernel<<<SCAN_NB, 256, 0, stream>>>(degi, slocal, spart);
    scan2_kernel<<<1, 256, 0, stream>>>(spart);
    scan3_kernel<<<SCAN_NB, 256, 0, stream>>>(slocal, spart, rowptr, cursor);
    fill_kernel<<<(N_EDGESC + 255) / 256, 256, 0, stream>>>(ei, cursor, col);

    // ---- layer 1 (K=768, A=x fp32) ----
    gemm_kernel<0, IN_DIMC><<<gemm_grid, 256, 0, stream>>>(x, Wb1, nullptr, Plb, Prb, M);
    agg_combine_kernel<<<agg_blocks, 128, 0, stream>>>(rowptr, col, Plb, Prb, b1, Hb, stats1, M);
    finalize_kernel<<<1, 128, 0, stream>>>(stats1, g1, be1, sc1, M);

    // ---- layer 2 (K=128, BN1+ReLU fused) ----
    gemm_kernel<1, HIDC><<<gemm_grid, 256, 0, stream>>>(Hb, Wb2, sc1, Plb, Prb, M);
    agg_combine_kernel<<<agg_blocks, 128, 0, stream>>>(rowptr, col, Plb, Prb, b2, Hb, stats2, M);
    finalize_kernel<<<1, 128, 0, stream>>>(stats2, g2, be2, sc2, M);

    // ---- layer 3 (K=128, BN2+ReLU fused) ----
    gemm_kernel<1, HIDC><<<gemm_grid, 256, 0, stream>>>(Hb, Wb3, sc2, Plb, Prb, M);
    agg_combine_kernel<<<agg_blocks, 128, 0, stream>>>(rowptr, col, Plb, Prb, b3, Hb, stats3, M);
    finalize_kernel<<<1, 128, 0, stream>>>(stats3, g3, be3, sc3, M);

    // ---- pool (BN3 fused) + head ----
    poolhead_kernel<<<N_GRAPHSC, 128, 0, stream>>>(Hb, sc3, batch, Wlin, blin, (float*)d_out, M);
}

// Round 11
// 574.470 us; speedup vs baseline: 2.3218x; 1.0217x over previous
//
#include <hip/hip_runtime.h>

#define N_NODESC 50000
#define N_EDGESC 400000
#define N_GRAPHSC 128
#define IN_DIMC 768
#define HIDC 128
#define NCLSC 11
#define BN_EPSC 1e-5f
#define NB_AGG 8
#define NREP 64
#define SCAN_NB ((N_NODESC + 255) / 256)

typedef __bf16 bf16_t;
typedef __bf16 bf16x2 __attribute__((ext_vector_type(2)));
typedef __bf16 bf16x8 __attribute__((ext_vector_type(8)));
typedef float f32x4 __attribute__((ext_vector_type(4)));

typedef __attribute__((address_space(1))) void glb_void;
typedef __attribute__((address_space(3))) void lds_void;

__device__ __forceinline__ void cp16(const void* g, void* l) {
    // async global->LDS, 16B/lane; LDS dst = wave-uniform base + lane*16
    __builtin_amdgcn_global_load_lds((glb_void*)g, (lds_void*)l, 16, 0, 0);
}

__device__ __forceinline__ f32x4 mfma_16x16x32_bf16(bf16x8 a, bf16x8 b, f32x4 c) {
    return __builtin_amdgcn_mfma_f32_16x16x32_bf16(a, b, c, 0, 0, 0);
}

// [Cl|Cr] = BN?(A)[M,K] @ Wb^T, Wb [256,K] bf16. Tile 128x128xBK32, grid (M/128, 2).
// MODE 0: A fp32, no BN. Depth-1 double-buffer at 48 KB LDS -> 3 blocks/CU
//   (R9 lesson: 64 KB depth-2 cut occupancy to 2 blocks/CU and was net-negative;
//    occupancy beats pipeline depth when DMA-concurrency-limited).
// MODE 1: A bf16; BN scale/shift computed IN-KERNEL from the stats replicas
//   (replaces a separate 1-block finalize dispatch), BN+ReLU applied
//   post-LDS-read; triple-buffered depth-2 (LDS ~49 KB, 3 blocks/CU).
// In-loop waits are raw s_waitcnt vmcnt(N) + s_barrier, never vmcnt(0) mid-loop.
template<int MODE, int KC>
__global__ __launch_bounds__(256) void gemm_kernel(const void* __restrict__ Av,
                                                   const bf16_t* __restrict__ Wb,
                                                   const float* __restrict__ stats,
                                                   const float* __restrict__ g,
                                                   const float* __restrict__ be,
                                                   bf16_t* __restrict__ Cl,
                                                   bf16_t* __restrict__ Cr,
                                                   int M)
{
    constexpr int NK   = KC / 32;
    constexpr int ASZ  = (MODE == 0) ? 16384 : 8192;   // one A buffer
    constexpr int BSZ  = 8192;                         // one B buffer
    constexpr int NAB  = (MODE == 0) ? 2 : 3;
    constexpr int NBB  = (MODE == 0) ? 2 : 3;
    constexpr int AISS = (MODE == 0) ? 4 : 2;
    constexpr int AKB  = (MODE == 0) ? 128 : 64;       // A bytes per k-iter along row
    constexpr int SCSZ = (MODE == 1) ? 1024 : 16;
    __shared__ __align__(16) unsigned char smem[NAB * ASZ + NBB * BSZ + SCSZ];
    unsigned char* Asm = smem;
    unsigned char* Bsm = smem + NAB * ASZ;
    float* scS = (float*)(smem + NAB * ASZ + NBB * BSZ);

    const int t    = threadIdx.x;
    const int m0   = blockIdx.x * 128;
    const int half = blockIdx.y;
    const int wid  = t >> 6;
    const int lane = t & 63;
    const int wm   = (wid >> 1) * 64;
    const int wn   = (wid & 1) * 64;
    const int l16  = lane & 15;
    const int quad = lane >> 4;

    // ---- async-loader sources (XOR swizzle folded into the global side) ----
    const char* aSrc[AISS]; int aDst[AISS];
#pragma unroll
    for (int s = 0; s < AISS; s++) {
        int L = (s * 4 + wid) * 64 + lane;   // 16B-chunk slot; LDS byte = L*16
        int r, c;
        if (MODE == 0) { r = L >> 3; c = (L & 7) ^ (r & 7); }         // 8 chunks/row (f32)
        else           { r = L >> 2; c = (L & 3) ^ ((r >> 1) & 3); }  // 4 chunks/row (bf16)
        int row = m0 + r; if (row > M - 1) row = M - 1;   // clamp; never stored
        if (MODE == 0) aSrc[s] = (const char*)Av + ((size_t)row * KC + (size_t)c * 4) * 4;
        else           aSrc[s] = (const char*)Av + ((size_t)row * KC + (size_t)c * 8) * 2;
        aDst[s] = (s * 4 + wid) * 1024;      // wave-uniform base
    }
    const char* bSrc[2]; int bDst[2];
#pragma unroll
    for (int s = 0; s < 2; s++) {
        int L = (s * 4 + wid) * 64 + lane;
        int r = L >> 2;
        int c = (L & 3) ^ ((r >> 1) & 3);
        bSrc[s] = (const char*)(Wb + (size_t)(half * 128 + r) * KC + c * 8);
        bDst[s] = (s * 4 + wid) * 1024;
    }

    // ---- fragment LDS byte offsets within one buffer ----
    int aOff[4][2], bOff[4];
#pragma unroll
    for (int i = 0; i < 4; i++) {
        int ra = wm + i * 16 + l16;
        if (MODE == 0) {
            aOff[i][0] = ra * 128 + (((2 * quad)     ^ (ra & 7)) * 16);
            aOff[i][1] = ra * 128 + (((2 * quad + 1) ^ (ra & 7)) * 16);
        } else {
            aOff[i][0] = ra * 64 + ((quad ^ ((ra >> 1) & 3)) * 16);
            aOff[i][1] = 0;
        }
        int rb = wn + i * 16 + l16;
        bOff[i] = rb * 64 + ((quad ^ ((rb >> 1) & 3)) * 16);
    }

    if (MODE == 1) {
        // fused BN finalize: reduce the NREP stat replicas -> scale/shift in LDS.
        // Regular vmem loads, fully drained before __syncthreads -> cp16 FIFO stays clean.
        if (t < HIDC) {
            float sum = 0.f, sumsq = 0.f;
            for (int r = 0; r < NREP; r++) {
                sum   += stats[r * 256 + t];
                sumsq += stats[r * 256 + HIDC + t];
            }
            float invM = 1.0f / (float)M;
            float mean = sum * invM;
            float var  = sumsq * invM - mean * mean;
            float s = rsqrtf(var + BN_EPSC) * g[t];
            scS[t] = s;
            scS[HIDC + t] = be[t] - mean * s;
        }
        __syncthreads();
    }

    f32x4 acc[4][4] = {};

    if constexpr (MODE == 0) {
        // ---- depth-1 double buffer: prologue A0,B0 ----
#pragma unroll
        for (int s = 0; s < 4; s++) cp16(aSrc[s], Asm + aDst[s]);
#pragma unroll
        for (int s = 0; s < 2; s++) cp16(bSrc[s], Bsm + bDst[s]);

        for (int it = 0; it < NK; ++it) {
            if (it + 1 < NK) {
                const size_t ka = (size_t)(it + 1) * 128;
                const size_t kb = (size_t)(it + 1) * 64;
                const int nb = (it + 1) & 1;
#pragma unroll
                for (int s = 0; s < 4; s++) cp16(aSrc[s] + ka, Asm + nb * ASZ + aDst[s]);
#pragma unroll
                for (int s = 0; s < 2; s++) cp16(bSrc[s] + kb, Bsm + nb * BSZ + bDst[s]);
                asm volatile("s_waitcnt vmcnt(6)" ::: "memory");   // drain iter-it only
            } else {
                asm volatile("s_waitcnt vmcnt(0)" ::: "memory");
            }
            asm volatile("s_barrier" ::: "memory");

            const unsigned char* Ab = Asm + (it & 1) * ASZ;
            const unsigned char* Bb = Bsm + (it & 1) * BSZ;
            bf16x8 af[4], bfr[4];
#pragma unroll
            for (int i = 0; i < 4; i++) {
                float4 u0 = *(const float4*)(Ab + aOff[i][0]);
                float4 u1 = *(const float4*)(Ab + aOff[i][1]);
                af[i][0] = (bf16_t)u0.x; af[i][1] = (bf16_t)u0.y;
                af[i][2] = (bf16_t)u0.z; af[i][3] = (bf16_t)u0.w;
                af[i][4] = (bf16_t)u1.x; af[i][5] = (bf16_t)u1.y;
                af[i][6] = (bf16_t)u1.z; af[i][7] = (bf16_t)u1.w;
            }
#pragma unroll
            for (int j = 0; j < 4; j++)
                bfr[j] = *(const bf16x8*)(Bb + bOff[j]);
#pragma unroll
            for (int i = 0; i < 4; i++)
#pragma unroll
                for (int j = 0; j < 4; j++)
                    acc[i][j] = mfma_16x16x32_bf16(af[i], bfr[j], acc[i][j]);

            asm volatile("s_barrier" ::: "memory");   // protect buf reused next iter
        }
    } else {
        // ---- depth-2 triple buffer (R9 structure) ----
#pragma unroll
        for (int s = 0; s < 2; s++) cp16(aSrc[s], Asm + aDst[s]);
#pragma unroll
        for (int s = 0; s < 2; s++) cp16(bSrc[s], Bsm + bDst[s]);
#pragma unroll
        for (int s = 0; s < 2; s++) cp16(aSrc[s] + 64, Asm + ASZ + aDst[s]);
#pragma unroll
        for (int s = 0; s < 2; s++) cp16(bSrc[s] + 64, Bsm + BSZ + bDst[s]);

        for (int it = 0; it < NK; ++it) {
            if (it + 2 < NK) {
                const size_t kb2 = (size_t)(it + 2) * 64;
                const int nb = (it + 2) % 3;
#pragma unroll
                for (int s = 0; s < 2; s++) cp16(aSrc[s] + kb2, Asm + nb * ASZ + aDst[s]);
#pragma unroll
                for (int s = 0; s < 2; s++) cp16(bSrc[s] + kb2, Bsm + nb * BSZ + bDst[s]);
                asm volatile("s_waitcnt vmcnt(8)" ::: "memory");
            } else if (it + 1 < NK) {
                asm volatile("s_waitcnt vmcnt(4)" ::: "memory");
            } else {
                asm volatile("s_waitcnt vmcnt(0)" ::: "memory");
            }
            asm volatile("s_barrier" ::: "memory");

            const unsigned char* Ab = Asm + (it % 3) * ASZ;
            const unsigned char* Bb = Bsm + (it % 3) * BSZ;
            bf16x8 af[4], bfr[4];
            float4 s0 = *(const float4*)&scS[it * 32 + quad * 8];
            float4 s1 = *(const float4*)&scS[it * 32 + quad * 8 + 4];
            float4 h0 = *(const float4*)&scS[HIDC + it * 32 + quad * 8];
            float4 h1 = *(const float4*)&scS[HIDC + it * 32 + quad * 8 + 4];
            float ss[8] = {s0.x, s0.y, s0.z, s0.w, s1.x, s1.y, s1.z, s1.w};
            float hh[8] = {h0.x, h0.y, h0.z, h0.w, h1.x, h1.y, h1.z, h1.w};
#pragma unroll
            for (int i = 0; i < 4; i++) {
                bf16x8 raw = *(const bf16x8*)(Ab + aOff[i][0]);
#pragma unroll
                for (int e = 0; e < 8; e++)
                    af[i][e] = (bf16_t)fmaxf(fmaf((float)raw[e], ss[e], hh[e]), 0.0f);
            }
#pragma unroll
            for (int j = 0; j < 4; j++)
                bfr[j] = *(const bf16x8*)(Bb + bOff[j]);
#pragma unroll
            for (int i = 0; i < 4; i++)
#pragma unroll
                for (int j = 0; j < 4; j++)
                    acc[i][j] = mfma_16x16x32_bf16(af[i], bfr[j], acc[i][j]);

            asm volatile("s_barrier" ::: "memory");
        }
    }

    // C/D layout (m89-verified, validated rounds 1-9)
    bf16_t* C = half ? Cr : Cl;
#pragma unroll
    for (int i = 0; i < 4; i++) {
        int rowb = m0 + wm + i * 16 + quad * 4;
#pragma unroll
        for (int j = 0; j < 4; j++) {
            int colh = wn + j * 16 + l16;
#pragma unroll
            for (int rr = 0; rr < 4; rr++) {
                int row = rowb + rr;
                if (row < M) C[(size_t)row * HIDC + colh] = (bf16_t)acc[i][j][rr];
            }
        }
    }
}

// ---------- fused init: weight converts + zero degi/stats ----------
__global__ void init_kernel(const float* __restrict__ W1l, const float* __restrict__ W1r,
                            const float* __restrict__ W2l, const float* __restrict__ W2r,
                            const float* __restrict__ W3l, const float* __restrict__ W3r,
                            bf16_t* __restrict__ Wb1, bf16_t* __restrict__ Wb2,
                            bf16_t* __restrict__ Wb3,
                            int* __restrict__ degi, float* __restrict__ stats)
{
    const int NW1 = 128 * IN_DIMC;
    const int NW2 = 128 * HIDC;
    const int NS  = 3 * NREP * 256;
    int j = blockIdx.x * blockDim.x + threadIdx.x;
    if (j < 2 * NW1) { Wb1[j] = (bf16_t)((j < NW1) ? W1l[j] : W1r[j - NW1]); return; }
    j -= 2 * NW1;
    if (j < 2 * NW2) { Wb2[j] = (bf16_t)((j < NW2) ? W2l[j] : W2r[j - NW2]); return; }
    j -= 2 * NW2;
    if (j < 2 * NW2) { Wb3[j] = (bf16_t)((j < NW2) ? W3l[j] : W3r[j - NW2]); return; }
    j -= 2 * NW2;
    if (j < NS) { stats[j] = 0.0f; return; }
    j -= NS;
    if (j < N_NODESC) degi[j] = 0;
}

// ---------- CSR build ----------
__global__ void degi_kernel(const int* __restrict__ ei, int* __restrict__ degi) {
    int e = blockIdx.x * blockDim.x + threadIdx.x;
    if (e < N_EDGESC) atomicAdd(&degi[ei[N_EDGESC + e]], 1);
}

__global__ __launch_bounds__(256) void scan1_kernel(const int* __restrict__ degi,
                                                    int* __restrict__ local,
                                                    int* __restrict__ partials)
{
    __shared__ int tmp[256];
    const int t = threadIdx.x;
    const int i = blockIdx.x * 256 + t;
    int v = (i < N_NODESC) ? degi[i] : 0;
    tmp[t] = v;
    __syncthreads();
    for (int off = 1; off < 256; off <<= 1) {
        int u = (t >= off) ? tmp[t - off] : 0;
        __syncthreads();
        tmp[t] += u;
        __syncthreads();
    }
    if (i < N_NODESC) local[i] = tmp[t] - v;
    if (t == 255) partials[blockIdx.x] = tmp[255];
}

// scan3 with the 196-partial scan folded in (replaces the scan2 dispatch):
// each block redundantly scans the partials in LDS (~1 us of work), then emits.
__global__ __launch_bounds__(256) void scan3_kernel(const int* __restrict__ local,
                                                    const int* __restrict__ partials,
                                                    int* __restrict__ rowptr,
                                                    int* __restrict__ cursor)
{
    __shared__ int inc[256];
    __shared__ int orig[256];
    const int t = threadIdx.x;
    int v = (t < SCAN_NB) ? partials[t] : 0;
    inc[t] = v; orig[t] = v;
    __syncthreads();
    for (int off = 1; off < 256; off <<= 1) {
        int u = (t >= off) ? inc[t - off] : 0;
        __syncthreads();
        inc[t] += u;
        __syncthreads();
    }
    const int boff = inc[blockIdx.x] - orig[blockIdx.x];   // exclusive offset, broadcast
    const int i = blockIdx.x * 256 + t;
    if (i < N_NODESC) {
        int r = local[i] + boff;
        rowptr[i] = r;
        cursor[i] = r;
    }
    if (i == 0) rowptr[N_NODESC] = N_EDGESC;
}

__global__ void fill_kernel(const int* __restrict__ ei, int* __restrict__ cursor,
                            int* __restrict__ col) {
    int e = blockIdx.x * blockDim.x + threadIdx.x;
    if (e >= N_EDGESC) return;
    int d = ei[N_EDGESC + e];
    int pos = atomicAdd(&cursor[d], 1);
    col[pos] = ei[e];
}

// ---------- fused CSR-gather mean-agg + bias + Pr + BN partial sums ----------
// NO device-scope fences (R8 lesson: per-block fences on 8-XCD CDNA cost ~250us/layer).
__global__ __launch_bounds__(128) void agg_combine_kernel(const int* __restrict__ rowptr,
                                                          const int* __restrict__ col,
                                                          const bf16_t* __restrict__ Plb,
                                                          const bf16_t* __restrict__ Prb,
                                                          const float* __restrict__ bias,
                                                          bf16_t* __restrict__ Hb,
                                                          float* __restrict__ stats, int M)
{
    const int lane = threadIdx.x & 63;
    const int wv   = threadIdx.x >> 6;
    const int c0   = lane * 2;
    const float b0 = bias[c0], b1v = bias[c0 + 1];
    float s0 = 0.f, s1 = 0.f, q0 = 0.f, q1 = 0.f;
    const int n0 = blockIdx.x * NB_AGG + wv * (NB_AGG / 2);
    for (int rr = 0; rr < NB_AGG / 2; rr++) {
        int n = n0 + rr;
        if (n >= M) break;
        int lo = rowptr[n], hi = rowptr[n + 1];
        float a0 = 0.f, a1 = 0.f;
        for (int e = lo; e < hi; e += 8) {
            int rem = hi - e;
            int idx[8];
#pragma unroll
            for (int j = 0; j < 8; j++) {
                int ee = e + j; if (ee > hi - 1) ee = hi - 1;
                idx[j] = col[ee];                 // broadcast loads
            }
            bf16x2 v[8];
#pragma unroll
            for (int j = 0; j < 8; j++)
                v[j] = *(const bf16x2*)&Plb[(size_t)idx[j] * HIDC + c0];  // 8 in flight
#pragma unroll
            for (int j = 0; j < 8; j++)
                if (j < rem) { a0 += (float)v[j][0]; a1 += (float)v[j][1]; }
        }
        int d = hi - lo;
        float inv = 1.0f / (float)(d > 0 ? d : 1);
        bf16x2 pr = *(const bf16x2*)&Prb[(size_t)n * HIDC + c0];
        float pre0 = fmaf(a0, inv, b0) + (float)pr[0];
        float pre1 = fmaf(a1, inv, b1v) + (float)pr[1];
        bf16x2 hv; hv[0] = (bf16_t)pre0; hv[1] = (bf16_t)pre1;
        *(bf16x2*)&Hb[(size_t)n * HIDC + c0] = hv;
        s0 += pre0; s1 += pre1; q0 += pre0 * pre0; q1 += pre1 * pre1;
    }
    const int rep = (blockIdx.x * 2 + wv) & (NREP - 1);
    atomicAdd(&stats[rep * 256 + c0], s0);
    atomicAdd(&stats[rep * 256 + c0 + 1], s1);
    atomicAdd(&stats[rep * 256 + HIDC + c0], q0);
    atomicAdd(&stats[rep * 256 + HIDC + c0 + 1], q1);
}

// ---------- fused BN3-finalize + pool + linear head ----------
__global__ __launch_bounds__(128) void poolhead_kernel(const bf16_t* __restrict__ Hb,
                                                       const float* __restrict__ stats,
                                                       const float* __restrict__ g,
                                                       const float* __restrict__ be,
                                                       const int* __restrict__ batch,
                                                       const float* __restrict__ Wlin,
                                                       const float* __restrict__ blin,
                                                       float* __restrict__ out, int M)
{
    __shared__ float sp[HIDC];
    int gph = blockIdx.x;
    int c   = threadIdx.x;
    // per-thread BN finalize for its channel (redundant per block, trivial)
    float sum = 0.f, sumsq = 0.f;
    for (int r = 0; r < NREP; r++) {
        sum   += stats[r * 256 + c];
        sumsq += stats[r * 256 + HIDC + c];
    }
    float invM = 1.0f / (float)M;
    float mean = sum * invM;
    float var  = sumsq * invM - mean * mean;
    float s = rsqrtf(var + BN_EPSC) * g[c];
    float h = be[c] - mean * s;

    int lo = 0, hi = M;
    while (lo < hi) { int m = (lo + hi) >> 1; if (batch[m] < gph) lo = m + 1; else hi = m; }
    int lo2 = lo, hi2 = M;
    while (lo2 < hi2) { int m = (lo2 + hi2) >> 1; if (batch[m] < gph + 1) lo2 = m + 1; else hi2 = m; }
    float mx = -INFINITY;
    for (int rr = lo; rr < lo2; rr++)
        mx = fmaxf(mx, fmaf((float)Hb[(size_t)rr * HIDC + c], s, h));
    sp[c] = mx;
    __syncthreads();
    if (c < NCLSC) {
        float acc = blin[c];
        for (int k = 0; k < HIDC; k++) acc += sp[k] * Wlin[c * HIDC + k];
        out[gph * NCLSC + c] = acc;
    }
}

extern "C" void kernel_launch(void* const* d_in, const int* in_sizes, int n_in,
                              void* d_out, int out_size, void* d_ws, size_t ws_size,
                              hipStream_t stream)
{
    const float* x     = (const float*)d_in[0];
    const int*   ei    = (const int*)d_in[1];
    const int*   batch = (const int*)d_in[2];
    const float* W1l = (const float*)d_in[3];
    const float* b1  = (const float*)d_in[4];
    const float* W1r = (const float*)d_in[5];
    const float* g1  = (const float*)d_in[6];
    const float* be1 = (const float*)d_in[7];
    const float* W2l = (const float*)d_in[8];
    const float* b2  = (const float*)d_in[9];
    const float* W2r = (const float*)d_in[10];
    const float* g2  = (const float*)d_in[11];
    const float* be2 = (const float*)d_in[12];
    const float* W3l = (const float*)d_in[13];
    const float* b3  = (const float*)d_in[14];
    const float* W3r = (const float*)d_in[15];
    const float* g3  = (const float*)d_in[16];
    const float* be3 = (const float*)d_in[17];
    const float* Wlin = (const float*)d_in[18];
    const float* blin = (const float*)d_in[19];

    const int M = N_NODESC;

    // workspace carve (16B aligned)
    char* w = (char*)d_ws;
    bf16_t* Plb  = (bf16_t*)w;  w += (size_t)M * HIDC * 2;
    bf16_t* Prb  = (bf16_t*)w;  w += (size_t)M * HIDC * 2;
    bf16_t* Hb   = (bf16_t*)w;  w += (size_t)M * HIDC * 2;
    bf16_t* Wb1  = (bf16_t*)w;  w += (size_t)256 * IN_DIMC * 2;
    bf16_t* Wb2  = (bf16_t*)w;  w += (size_t)256 * HIDC * 2;
    bf16_t* Wb3  = (bf16_t*)w;  w += (size_t)256 * HIDC * 2;
    int*   rowptr= (int*)w;     w += (size_t)(M + 16) * 4;
    int*   col   = (int*)w;     w += (size_t)N_EDGESC * 4;
    int*   cursor= (int*)w;     w += (size_t)M * 4;
    int*   degi  = (int*)w;     w += (size_t)M * 4;
    int*   slocal= (int*)w;     w += (size_t)M * 4;
    int*   spart = (int*)w;     w += 256 * 4;
    float* stats = (float*)w;   w += (size_t)3 * NREP * 256 * 4;   // zeroed in init

    float* stats1 = stats;
    float* stats2 = stats + NREP * 256;
    float* stats3 = stats + 2 * NREP * 256;

    const dim3 gemm_grid((M + 127) / 128, 2);
    const int agg_blocks = (M + NB_AGG - 1) / NB_AGG;
    const int init_total = 2 * 128 * IN_DIMC + 4 * 128 * HIDC + 3 * NREP * 256 + M;

    // ---- init (weights + zeros, one dispatch) ----
    init_kernel<<<(init_total + 255) / 256, 256, 0, stream>>>(W1l, W1r, W2l, W2r, W3l, W3r,
                                                              Wb1, Wb2, Wb3, degi, stats);
    // ---- CSR build (4 dispatches) ----
    degi_kernel<<<(N_EDGESC + 255) / 256, 256, 0, stream>>>(ei, degi);
    scan1_kernel<<<SCAN_NB, 256, 0, stream>>>(degi, slocal, spart);
    scan3_kernel<<<SCAN_NB, 256, 0, stream>>>(slocal, spart, rowptr, cursor);
    fill_kernel<<<(N_EDGESC + 255) / 256, 256, 0, stream>>>(ei, cursor, col);

    // ---- layer 1 (K=768, A=x fp32) ----
    gemm_kernel<0, IN_DIMC><<<gemm_grid, 256, 0, stream>>>(x, Wb1, nullptr, nullptr, nullptr,
                                                           Plb, Prb, M);
    agg_combine_kernel<<<agg_blocks, 128, 0, stream>>>(rowptr, col, Plb, Prb, b1, Hb, stats1, M);

    // ---- layer 2 (K=128; BN1 finalize + BN1+ReLU fused into the GEMM) ----
    gemm_kernel<1, HIDC><<<gemm_grid, 256, 0, stream>>>(Hb, Wb2, stats1, g1, be1, Plb, Prb, M);
    agg_combine_kernel<<<agg_blocks, 128, 0, stream>>>(rowptr, col, Plb, Prb, b2, Hb, stats2, M);

    // ---- layer 3 (K=128; BN2 finalize + BN2+ReLU fused) ----
    gemm_kernel<1, HIDC><<<gemm_grid, 256, 0, stream>>>(Hb, Wb3, stats2, g2, be2, Plb, Prb, M);
    agg_combine_kernel<<<agg_blocks, 128, 0, stream>>>(rowptr, col, Plb, Prb, b3, Hb, stats3, M);

    // ---- BN3 finalize + pool + head (one dispatch) ----
    poolhead_kernel<<<N_GRAPHSC, 128, 0, stream>>>(Hb, stats3, g3, be3, batch, Wlin, blin,
                                                   (float*)d_out, M);
}